// Round 1
// baseline (6172.789 us; speedup 1.0000x reference)
//
#include <hip/hip_runtime.h>
#include <hip/hip_bf16.h>

#define B_ 4
#define T_ 2048
#define E_ 1024
#define H_ 16
#define D_ 64
#define M_ (B_*T_)   // 8192 rows

// ---------------------------------------------------------------------------
// Kernel 1: QKV projection.  q[b,h,t,d] = sum_e x[b,t,e] * Wq[h,e,d]
// GEMM view: C[m, h*64+d], m = b*T+t.  N-tile (64) == one head.
// Output stored bf16 in [B,H,T,D] layout for the attention kernel.
// grid = (M/64, H, 3), block = 256
// ---------------------------------------------------------------------------
__global__ void qkv_gemm(const float* __restrict__ x,
                         const float* __restrict__ Wq,
                         const float* __restrict__ Wk,
                         const float* __restrict__ Wv,
                         __hip_bfloat16* __restrict__ q,
                         __hip_bfloat16* __restrict__ k,
                         __hip_bfloat16* __restrict__ v) {
    const int which = blockIdx.z;
    const float* __restrict__ W = (which == 0) ? Wq : (which == 1) ? Wk : Wv;
    __hip_bfloat16* __restrict__ out = (which == 0) ? q : (which == 1) ? k : v;

    const int h  = blockIdx.y;
    const int m0 = blockIdx.x * 64;

    __shared__ float As[16][65];   // [kk][m] (+1 pad breaks 16-way write conflict)
    __shared__ float Bs[16][65];   // [kk][j]

    const int tid = threadIdx.x;
    const int tx = tid & 15, ty = tid >> 4;

    float acc[4][4] = {};

    const size_t wbase = (size_t)h * E_ * D_;

    for (int k0 = 0; k0 < E_; k0 += 16) {
#pragma unroll
        for (int r = 0; r < 4; ++r) {
            int idx = tid + r * 256;          // 0..1023
            int mm = idx >> 4, kk = idx & 15;
            As[kk][mm] = x[(size_t)(m0 + mm) * E_ + k0 + kk];
        }
#pragma unroll
        for (int r = 0; r < 4; ++r) {
            int idx = tid + r * 256;
            int kk = idx >> 6, j = idx & 63;
            Bs[kk][j] = W[wbase + (size_t)(k0 + kk) * D_ + j];
        }
        __syncthreads();
#pragma unroll
        for (int kk = 0; kk < 16; ++kk) {
            float a[4], bb[4];
#pragma unroll
            for (int i = 0; i < 4; ++i) a[i] = As[kk][ty * 4 + i];
#pragma unroll
            for (int j = 0; j < 4; ++j) bb[j] = Bs[kk][tx * 4 + j];
#pragma unroll
            for (int i = 0; i < 4; ++i)
#pragma unroll
                for (int j = 0; j < 4; ++j) acc[i][j] += a[i] * bb[j];
        }
        __syncthreads();
    }

#pragma unroll
    for (int i = 0; i < 4; ++i) {
        int m = m0 + ty * 4 + i;
        int b = m / T_, t = m % T_;
        size_t base = (((size_t)b * H_ + h) * T_ + t) * D_;
#pragma unroll
        for (int j = 0; j < 4; ++j)
            out[base + tx * 4 + j] = __float2bfloat16(acc[i][j]);
    }
}

// ---------------------------------------------------------------------------
// Kernel 2: causal attention, one block (256 thr) per (b,h,t) query row.
// scores -> LDS (<= 8KB), block max/sum reduce, then PV with 4-way d-groups.
// attn output layout: [b][t][h*D+d]  (i.e. [M][E]) fp32, ready for out proj.
// grid = (T, H, B)
// ---------------------------------------------------------------------------
__global__ void attn_kernel(const __hip_bfloat16* __restrict__ q,
                            const __hip_bfloat16* __restrict__ k,
                            const __hip_bfloat16* __restrict__ v,
                            const float* __restrict__ mask,
                            float* __restrict__ attn) {
    const int t = blockIdx.x;
    const int h = blockIdx.y;
    const int b = blockIdx.z;
    const int tid = threadIdx.x;

    __shared__ float s_sc[T_];        // 8 KB scores
    __shared__ float s_q[D_];
    __shared__ float s_red[8];        // 4 wave maxes + 4 wave sums
    __shared__ float s_vred[4][D_];

    const size_t bh = ((size_t)b * H_ + h) * T_;

    if (tid < D_) s_q[tid] = __bfloat162float(q[(bh + t) * D_ + tid]);
    __syncthreads();

    const int n = t + 1;              // causal: keys 0..t
    float lmax = -INFINITY;
    for (int s = tid; s < n; s += 256) {
        const __hip_bfloat16* kr = k + (bh + s) * D_;
        float dot = 0.f;
#pragma unroll
        for (int d = 0; d < D_; ++d)
            dot += s_q[d] * __bfloat162float(kr[d]);
        float sc = dot * 0.125f
                 + (1.0f - mask[b * T_ + s]) * -3.402823466e38f;
        s_sc[s] = sc;
        lmax = fmaxf(lmax, sc);
    }
    const int wave = tid >> 6, lane = tid & 63;
#pragma unroll
    for (int off = 32; off > 0; off >>= 1)
        lmax = fmaxf(lmax, __shfl_down(lmax, off, 64));
    if (lane == 0) s_red[wave] = lmax;
    __syncthreads();
    const float bmax = fmaxf(fmaxf(s_red[0], s_red[1]),
                             fmaxf(s_red[2], s_red[3]));

    float lsum = 0.f;
    for (int s = tid; s < n; s += 256) {
        float e = __expf(s_sc[s] - bmax);
        s_sc[s] = e;          // same indices this thread wrote: no hazard
        lsum += e;
    }
#pragma unroll
    for (int off = 32; off > 0; off >>= 1)
        lsum += __shfl_down(lsum, off, 64);
    if (lane == 0) s_red[4 + wave] = lsum;
    __syncthreads();          // covers s_sc exp-writes AND s_red sums
    const float inv = 1.0f / (s_red[4] + s_red[5] + s_red[6] + s_red[7]);

    // PV: thread (g,d): g = tid/64 strides over s, d = tid%64
    const int d = tid & 63, g = tid >> 6;
    float acc = 0.f;
    for (int s = g; s < n; s += 4)
        acc += s_sc[s] * __bfloat162float(v[(bh + s) * D_ + d]);
    s_vred[g][d] = acc;
    __syncthreads();
    if (g == 0) {
        float o = (s_vred[0][d] + s_vred[1][d] + s_vred[2][d] + s_vred[3][d]) * inv;
        attn[((size_t)b * T_ + t) * E_ + h * D_ + d] = o;
    }
}

// ---------------------------------------------------------------------------
// Kernel 3: output projection.  C[m,n] = sum_k A[m,k] * Wo[n,k] + bo[n]
// grid = (M/64, E/64), block = 256
// ---------------------------------------------------------------------------
__global__ void out_gemm(const float* __restrict__ A,
                         const float* __restrict__ Wo,
                         const float* __restrict__ bo,
                         float* __restrict__ C) {
    const int m0 = blockIdx.x * 64;
    const int n0 = blockIdx.y * 64;

    __shared__ float As[16][65];
    __shared__ float Bs[16][65];   // Bs[kk][j] = Wo[(n0+j)*E + k0+kk]

    const int tid = threadIdx.x;
    const int tx = tid & 15, ty = tid >> 4;

    float acc[4][4] = {};

    for (int k0 = 0; k0 < E_; k0 += 16) {
#pragma unroll
        for (int r = 0; r < 4; ++r) {
            int idx = tid + r * 256;
            int mm = idx >> 4, kk = idx & 15;
            As[kk][mm] = A[(size_t)(m0 + mm) * E_ + k0 + kk];
        }
#pragma unroll
        for (int r = 0; r < 4; ++r) {
            int idx = tid + r * 256;
            int j = idx >> 4, kk = idx & 15;
            Bs[kk][j] = Wo[(size_t)(n0 + j) * E_ + k0 + kk];
        }
        __syncthreads();
#pragma unroll
        for (int kk = 0; kk < 16; ++kk) {
            float a[4], bb[4];
#pragma unroll
            for (int i = 0; i < 4; ++i) a[i] = As[kk][ty * 4 + i];
#pragma unroll
            for (int j = 0; j < 4; ++j) bb[j] = Bs[kk][tx * 4 + j];
#pragma unroll
            for (int i = 0; i < 4; ++i)
#pragma unroll
                for (int j = 0; j < 4; ++j) acc[i][j] += a[i] * bb[j];
        }
        __syncthreads();
    }

#pragma unroll
    for (int i = 0; i < 4; ++i) {
        int m = m0 + ty * 4 + i;
#pragma unroll
        for (int j = 0; j < 4; ++j) {
            int n = n0 + tx * 4 + j;
            C[(size_t)m * E_ + n] = acc[i][j] + bo[n];
        }
    }
}

// ---------------------------------------------------------------------------
extern "C" void kernel_launch(void* const* d_in, const int* in_sizes, int n_in,
                              void* d_out, int out_size, void* d_ws, size_t ws_size,
                              hipStream_t stream) {
    const float* x    = (const float*)d_in[0];
    const float* mask = (const float*)d_in[1];
    const float* Wq   = (const float*)d_in[2];
    const float* Wk   = (const float*)d_in[3];
    const float* Wv   = (const float*)d_in[4];
    const float* Wo   = (const float*)d_in[5];
    const float* bo   = (const float*)d_in[6];
    float* out        = (float*)d_out;

    // workspace layout: q,k,v bf16 [B,H,T,D] then attn fp32 [M,E]
    const size_t qkv_elems = (size_t)M_ * E_;          // 8.4M
    char* ws = (char*)d_ws;
    __hip_bfloat16* q = (__hip_bfloat16*)ws;
    __hip_bfloat16* k = (__hip_bfloat16*)(ws + qkv_elems * 2);
    __hip_bfloat16* v = (__hip_bfloat16*)(ws + qkv_elems * 4);
    float* attn       = (float*)(ws + qkv_elems * 6);

    qkv_gemm<<<dim3(M_ / 64, H_, 3), 256, 0, stream>>>(x, Wq, Wk, Wv, q, k, v);
    attn_kernel<<<dim3(T_, H_, B_), 256, 0, stream>>>(q, k, v, mask, attn);
    out_gemm<<<dim3(M_ / 64, E_ / 64), 256, 0, stream>>>(attn, Wo, bo, out);
}

// Round 2
// 1753.968 us; speedup vs baseline: 3.5193x; 3.5193x over previous
//
#include <hip/hip_runtime.h>
#include <hip/hip_bf16.h>

#define B_ 4
#define T_ 2048
#define E_ 1024
#define H_ 16
#define D_ 64
#define M_ (B_*T_)   // 8192 rows

typedef short bf16x8 __attribute__((ext_vector_type(8)));
typedef float f32x4  __attribute__((ext_vector_type(4)));

__device__ __forceinline__ short f2bf(float f) {
    __hip_bfloat16 h = __float2bfloat16(f);
    return *reinterpret_cast<short*>(&h);
}

// ---------------------------------------------------------------------------
// Kernel 1: QKV projection (unchanged this round).
// q[b,h,t,d] = sum_e x[b,t,e] * Wq[h,e,d];  output bf16 [B,H,T,D].
// grid = (M/64, H, 3), block = 256
// ---------------------------------------------------------------------------
__global__ void qkv_gemm(const float* __restrict__ x,
                         const float* __restrict__ Wq,
                         const float* __restrict__ Wk,
                         const float* __restrict__ Wv,
                         __hip_bfloat16* __restrict__ q,
                         __hip_bfloat16* __restrict__ k,
                         __hip_bfloat16* __restrict__ v) {
    const int which = blockIdx.z;
    const float* __restrict__ W = (which == 0) ? Wq : (which == 1) ? Wk : Wv;
    __hip_bfloat16* __restrict__ out = (which == 0) ? q : (which == 1) ? k : v;

    const int h  = blockIdx.y;
    const int m0 = blockIdx.x * 64;

    __shared__ float As[16][65];
    __shared__ float Bs[16][65];

    const int tid = threadIdx.x;
    const int tx = tid & 15, ty = tid >> 4;

    float acc[4][4] = {};
    const size_t wbase = (size_t)h * E_ * D_;

    for (int k0 = 0; k0 < E_; k0 += 16) {
#pragma unroll
        for (int r = 0; r < 4; ++r) {
            int idx = tid + r * 256;
            int mm = idx >> 4, kk = idx & 15;
            As[kk][mm] = x[(size_t)(m0 + mm) * E_ + k0 + kk];
        }
#pragma unroll
        for (int r = 0; r < 4; ++r) {
            int idx = tid + r * 256;
            int kk = idx >> 6, j = idx & 63;
            Bs[kk][j] = W[wbase + (size_t)(k0 + kk) * D_ + j];
        }
        __syncthreads();
#pragma unroll
        for (int kk = 0; kk < 16; ++kk) {
            float a[4], bb[4];
#pragma unroll
            for (int i = 0; i < 4; ++i) a[i] = As[kk][ty * 4 + i];
#pragma unroll
            for (int j = 0; j < 4; ++j) bb[j] = Bs[kk][tx * 4 + j];
#pragma unroll
            for (int i = 0; i < 4; ++i)
#pragma unroll
                for (int j = 0; j < 4; ++j) acc[i][j] += a[i] * bb[j];
        }
        __syncthreads();
    }

#pragma unroll
    for (int i = 0; i < 4; ++i) {
        int m = m0 + ty * 4 + i;
        int b = m / T_, t = m % T_;
        size_t base = (((size_t)b * H_ + h) * T_ + t) * D_;
#pragma unroll
        for (int j = 0; j < 4; ++j)
            out[base + tx * 4 + j] = __float2bfloat16(acc[i][j]);
    }
}

// ---------------------------------------------------------------------------
// Kernel 2: flash attention with bf16 MFMA.
// Block = 256 thr (4 waves). Block owns (b, h, 64 Q rows); wave owns 16 rows.
// K-tile = 32 keys/iter. QK^T and PV via mfma_f32_16x16x32_bf16.
// Layouts (guide §3, m89/m120-verified):
//   A[m=lane&15][k=quad*8+j]   B[k=quad*8+j][n=lane&15]   C: col=lane&15,row=quad*4+reg
// K loads direct from global (A/B layouts coincide for 16x16 => no transpose).
// V staged transposed in LDS (VT[d][s]); P round-trips C-layout->LDS->A-layout.
// grid = (T/64, H, B) with reversed x so longest (most K-tiles) launch first.
// ---------------------------------------------------------------------------
#define VT_PITCH 48   // shorts; 96B rows, 16B-aligned fragment reads
#define P_PITCH  40   // shorts; 80B rows, 16B-aligned fragment reads

__global__ __launch_bounds__(256) void flash_attn(
        const __hip_bfloat16* __restrict__ qg,
        const __hip_bfloat16* __restrict__ kg,
        const __hip_bfloat16* __restrict__ vg,
        const float* __restrict__ mask,
        float* __restrict__ attn) {
    const int h = blockIdx.y, b = blockIdx.z;
    const int t0 = (int)(gridDim.x - 1 - blockIdx.x) * 64;
    const int tid  = threadIdx.x;
    const int wave = tid >> 6, lane = tid & 63;
    const int c = lane & 15, quad = lane >> 4;

    __shared__ short VT[64 * VT_PITCH];        // 6 KB
    __shared__ short Pb[4 * 16 * P_PITCH];     // 5 KB

    const size_t bh = ((size_t)b * H_ + h) * T_;
    const short* q = (const short*)qg;
    const short* k = (const short*)kg;
    const short* v = (const short*)vg;

    // Q fragments (A operand), persistent: row m = lane&15 within wave's 16
    const int qrow = t0 + wave * 16 + c;
    const bf16x8 a0 = *(const bf16x8*)(q + (bh + qrow) * D_ + quad * 8);
    const bf16x8 a1 = *(const bf16x8*)(q + (bh + qrow) * D_ + 32 + quad * 8);

    f32x4 o0 = {0,0,0,0}, o1 = {0,0,0,0}, o2 = {0,0,0,0}, o3 = {0,0,0,0};
    float m_s[4] = {-INFINITY, -INFINITY, -INFINITY, -INFINITY};
    float l_s[4] = {0.f, 0.f, 0.f, 0.f};

    const int n_tiles = t0 / 32 + 2;           // keys 0 .. t0+63
    const int vrow = tid >> 3;                 // V staging: 0..31
    const int vd0  = (tid & 7) * 8;

    for (int it = 0; it < n_tiles; ++it) {
        const int s0 = it * 32;

        // ---- stage V tile transposed: VT[d][s] ----
        bf16x8 vv = *(const bf16x8*)(v + (bh + s0 + vrow) * D_ + vd0);
#pragma unroll
        for (int j = 0; j < 8; ++j)
            VT[(vd0 + j) * VT_PITCH + vrow] = vv[j];

        // ---- K fragments (B operand) direct from global ----
        const bf16x8 bx0 = *(const bf16x8*)(k + (bh + s0 + c) * D_ + quad * 8);
        const bf16x8 bx1 = *(const bf16x8*)(k + (bh + s0 + c) * D_ + 32 + quad * 8);
        const bf16x8 by0 = *(const bf16x8*)(k + (bh + s0 + 16 + c) * D_ + quad * 8);
        const bf16x8 by1 = *(const bf16x8*)(k + (bh + s0 + 16 + c) * D_ + 32 + quad * 8);

        f32x4 sx = {0,0,0,0}, sy = {0,0,0,0};
        sx = __builtin_amdgcn_mfma_f32_16x16x32_bf16(a0, bx0, sx, 0, 0, 0);
        sx = __builtin_amdgcn_mfma_f32_16x16x32_bf16(a1, bx1, sx, 0, 0, 0);
        sy = __builtin_amdgcn_mfma_f32_16x16x32_bf16(a0, by0, sy, 0, 0, 0);
        sy = __builtin_amdgcn_mfma_f32_16x16x32_bf16(a1, by1, sy, 0, 0, 0);

        // padding-mask bias per key
        const float biasX = (1.0f - mask[(size_t)b * T_ + s0 + c])      * -3.402823466e38f;
        const float biasY = (1.0f - mask[(size_t)b * T_ + s0 + 16 + c]) * -3.402823466e38f;

        float pX[4], pY[4], alpha[4];
#pragma unroll
        for (int i = 0; i < 4; ++i) {
            const int tr = t0 + wave * 16 + quad * 4 + i;   // global query row
            float vx = sx[i] * 0.125f + biasX;
            float vy = sy[i] * 0.125f + biasY;
            if (s0 + c > tr)      vx = -INFINITY;           // causal
            if (s0 + 16 + c > tr) vy = -INFINITY;
            float mx = fmaxf(vx, vy);
            mx = fmaxf(mx, __shfl_xor(mx, 1));
            mx = fmaxf(mx, __shfl_xor(mx, 2));
            mx = fmaxf(mx, __shfl_xor(mx, 4));
            mx = fmaxf(mx, __shfl_xor(mx, 8));
            const float mnew = fmaxf(m_s[i], mx);
            const float cm   = fmaxf(mnew, -1e30f);         // NaN guard
            alpha[i] = __expf(fmaxf(m_s[i], -1e30f) - cm);
            m_s[i] = mnew;
            const float ex = __expf(vx - cm);               // -inf -> 0
            const float ey = __expf(vy - cm);
            pX[i] = ex; pY[i] = ey;
            float rs = ex + ey;
            rs += __shfl_xor(rs, 1);
            rs += __shfl_xor(rs, 2);
            rs += __shfl_xor(rs, 4);
            rs += __shfl_xor(rs, 8);
            l_s[i] = l_s[i] * alpha[i] + rs;
        }
#pragma unroll
        for (int i = 0; i < 4; ++i) {
            o0[i] *= alpha[i]; o1[i] *= alpha[i];
            o2[i] *= alpha[i]; o3[i] *= alpha[i];
        }

        // ---- P: C-layout -> LDS (bf16), per-wave region ----
        short* P = Pb + wave * 16 * P_PITCH;
#pragma unroll
        for (int i = 0; i < 4; ++i) {
            P[(quad * 4 + i) * P_PITCH + c]      = f2bf(pX[i]);
            P[(quad * 4 + i) * P_PITCH + 16 + c] = f2bf(pY[i]);
        }

        __syncthreads();   // VT writes + P writes visible

        // ---- PV: A = P (A-layout), B = V from VT ----
        const bf16x8 pf  = *(const bf16x8*)(P + c * P_PITCH + quad * 8);
        const bf16x8 v0f = *(const bf16x8*)(&VT[(0*16 + c) * VT_PITCH + quad * 8]);
        const bf16x8 v1f = *(const bf16x8*)(&VT[(1*16 + c) * VT_PITCH + quad * 8]);
        const bf16x8 v2f = *(const bf16x8*)(&VT[(2*16 + c) * VT_PITCH + quad * 8]);
        const bf16x8 v3f = *(const bf16x8*)(&VT[(3*16 + c) * VT_PITCH + quad * 8]);

        o0 = __builtin_amdgcn_mfma_f32_16x16x32_bf16(pf, v0f, o0, 0, 0, 0);
        o1 = __builtin_amdgcn_mfma_f32_16x16x32_bf16(pf, v1f, o1, 0, 0, 0);
        o2 = __builtin_amdgcn_mfma_f32_16x16x32_bf16(pf, v2f, o2, 0, 0, 0);
        o3 = __builtin_amdgcn_mfma_f32_16x16x32_bf16(pf, v3f, o3, 0, 0, 0);

        __syncthreads();   // protect VT/P before next iteration's staging
    }

    // epilogue: normalize, store [b][t][h*64+d] fp32
#pragma unroll
    for (int i = 0; i < 4; ++i) {
        const int t = t0 + wave * 16 + quad * 4 + i;
        const float invl = 1.0f / l_s[i];
        const size_t base = ((size_t)b * T_ + t) * E_ + h * D_;
        attn[base + 0*16 + c] = o0[i] * invl;
        attn[base + 1*16 + c] = o1[i] * invl;
        attn[base + 2*16 + c] = o2[i] * invl;
        attn[base + 3*16 + c] = o3[i] * invl;
    }
}

// ---------------------------------------------------------------------------
// Kernel 3: output projection (unchanged this round).
// grid = (M/64, E/64), block = 256
// ---------------------------------------------------------------------------
__global__ void out_gemm(const float* __restrict__ A,
                         const float* __restrict__ Wo,
                         const float* __restrict__ bo,
                         float* __restrict__ C) {
    const int m0 = blockIdx.x * 64;
    const int n0 = blockIdx.y * 64;

    __shared__ float As[16][65];
    __shared__ float Bs[16][65];

    const int tid = threadIdx.x;
    const int tx = tid & 15, ty = tid >> 4;

    float acc[4][4] = {};

    for (int k0 = 0; k0 < E_; k0 += 16) {
#pragma unroll
        for (int r = 0; r < 4; ++r) {
            int idx = tid + r * 256;
            int mm = idx >> 4, kk = idx & 15;
            As[kk][mm] = A[(size_t)(m0 + mm) * E_ + k0 + kk];
        }
#pragma unroll
        for (int r = 0; r < 4; ++r) {
            int idx = tid + r * 256;
            int j = idx >> 4, kk = idx & 15;
            Bs[kk][j] = Wo[(size_t)(n0 + j) * E_ + k0 + kk];
        }
        __syncthreads();
#pragma unroll
        for (int kk = 0; kk < 16; ++kk) {
            float a[4], bb[4];
#pragma unroll
            for (int i = 0; i < 4; ++i) a[i] = As[kk][ty * 4 + i];
#pragma unroll
            for (int j = 0; j < 4; ++j) bb[j] = Bs[kk][tx * 4 + j];
#pragma unroll
            for (int i = 0; i < 4; ++i)
#pragma unroll
                for (int j = 0; j < 4; ++j) acc[i][j] += a[i] * bb[j];
        }
        __syncthreads();
    }

#pragma unroll
    for (int i = 0; i < 4; ++i) {
        int m = m0 + ty * 4 + i;
#pragma unroll
        for (int j = 0; j < 4; ++j) {
            int n = n0 + tx * 4 + j;
            C[(size_t)m * E_ + n] = acc[i][j] + bo[n];
        }
    }
}

// ---------------------------------------------------------------------------
extern "C" void kernel_launch(void* const* d_in, const int* in_sizes, int n_in,
                              void* d_out, int out_size, void* d_ws, size_t ws_size,
                              hipStream_t stream) {
    const float* x    = (const float*)d_in[0];
    const float* mask = (const float*)d_in[1];
    const float* Wq   = (const float*)d_in[2];
    const float* Wk   = (const float*)d_in[3];
    const float* Wv   = (const float*)d_in[4];
    const float* Wo   = (const float*)d_in[5];
    const float* bo   = (const float*)d_in[6];
    float* out        = (float*)d_out;

    const size_t qkv_elems = (size_t)M_ * E_;
    char* ws = (char*)d_ws;
    __hip_bfloat16* q = (__hip_bfloat16*)ws;
    __hip_bfloat16* k = (__hip_bfloat16*)(ws + qkv_elems * 2);
    __hip_bfloat16* v = (__hip_bfloat16*)(ws + qkv_elems * 4);
    float* attn       = (float*)(ws + qkv_elems * 6);

    qkv_gemm<<<dim3(M_ / 64, H_, 3), 256, 0, stream>>>(x, Wq, Wk, Wv, q, k, v);
    flash_attn<<<dim3(T_ / 64, H_, B_), 256, 0, stream>>>(q, k, v, mask, attn);
    out_gemm<<<dim3(M_ / 64, E_ / 64), 256, 0, stream>>>(attn, Wo, bo, out);
}

// Round 3
// 556.330 us; speedup vs baseline: 11.0956x; 3.1527x over previous
//
#include <hip/hip_runtime.h>
#include <hip/hip_bf16.h>

#define B_ 4
#define T_ 2048
#define E_ 1024
#define H_ 16
#define D_ 64
#define M_ (B_*T_)   // 8192 rows

typedef short bf16x8 __attribute__((ext_vector_type(8)));
typedef float f32x4  __attribute__((ext_vector_type(4)));

__device__ __forceinline__ short f2bf(float f) {
    __hip_bfloat16 h = __float2bfloat16(f);
    return *reinterpret_cast<short*>(&h);
}

__device__ __forceinline__ void async_ld16(const void* g, void* l) {
    __builtin_amdgcn_global_load_lds(
        (const __attribute__((address_space(1))) unsigned int*)g,
        (__attribute__((address_space(3))) unsigned int*)l, 16, 0, 0);
}

// ---------------------------------------------------------------------------
// Prep 1: fp32 -> bf16 elementwise (x and Wo). Each thread converts 4 elems.
// ---------------------------------------------------------------------------
__global__ void conv_bf16(const float* __restrict__ src, short* __restrict__ dst) {
    const int i = blockIdx.x * 256 + threadIdx.x;
    float4 v = ((const float4*)src)[i];
    short4 o = make_short4(f2bf(v.x), f2bf(v.y), f2bf(v.z), f2bf(v.w));
    ((short4*)dst)[i] = o;
}

// ---------------------------------------------------------------------------
// Prep 2: Wq/Wk/Wv [H][E][D] fp32 -> Wt [3*1024 n][1024 e] bf16, n = h*64+d.
// 64x64 LDS tile transpose.  grid (E/64, H, 3), block 256.
// ---------------------------------------------------------------------------
__global__ void wtrans(const float* __restrict__ Wq,
                       const float* __restrict__ Wk,
                       const float* __restrict__ Wv,
                       short* __restrict__ Wt) {
    const int which = blockIdx.z;
    const float* __restrict__ W = (which == 0) ? Wq : (which == 1) ? Wk : Wv;
    const int h  = blockIdx.y;
    const int e0 = blockIdx.x * 64;

    __shared__ float tile[64][65];
    const int tid = threadIdx.x;

#pragma unroll
    for (int r = 0; r < 4; ++r) {
        int lin = tid + r * 256;               // 0..1023
        int er = lin >> 4, c4 = (lin & 15) * 4;
        float4 v = *(const float4*)(W + ((size_t)h * E_ + e0 + er) * D_ + c4);
        tile[er][c4 + 0] = v.x; tile[er][c4 + 1] = v.y;
        tile[er][c4 + 2] = v.z; tile[er][c4 + 3] = v.w;
    }
    __syncthreads();
#pragma unroll
    for (int r = 0; r < 4; ++r) {
        int lin = tid + r * 256;
        int dr = lin >> 4, j4 = (lin & 15) * 4;
        short4 o = make_short4(f2bf(tile[j4 + 0][dr]), f2bf(tile[j4 + 1][dr]),
                               f2bf(tile[j4 + 2][dr]), f2bf(tile[j4 + 3][dr]));
        *(short4*)(Wt + ((size_t)which * 1024 + h * 64 + dr) * E_ + e0 + j4) = o;
    }
}

// ---------------------------------------------------------------------------
// MFMA GEMM, m97 structure: 128x128 tile, BK=32, global_load_lds width 16,
// 4 waves in 2x2, each 64x64 = 4x4 mfma_f32_16x16x32_bf16 tiles.
// A [M][1024] bf16 row-major; Bt [N][1024] bf16 row-major (N-major, k contig).
// LDS chunk swizzle (on global side): kg = (p&3) ^ ((row>>1)&3) -> 2-way-free
// ds_read_b128 at fragment time.
// MODE 0: C -> q/k/v bf16 [B,H,T,D] scatter (which = n-block / 1024)
// MODE 1: C -> fp32 [M][E] + bias
// ---------------------------------------------------------------------------
template <int MODE>
__global__ __launch_bounds__(256) void mfma_gemm(
        const short* __restrict__ A,
        const short* __restrict__ Bt,
        short* __restrict__ qo, short* __restrict__ ko, short* __restrict__ vo,
        float* __restrict__ Cout, const float* __restrict__ bo) {
    __shared__ __align__(16) short As[128 * 32];
    __shared__ __align__(16) short Bs[128 * 32];

    const int tid  = threadIdx.x;
    const int wave = tid >> 6, lane = tid & 63;
    const int c = lane & 15, quad = lane >> 4;
    const int wm = wave >> 1, wn = wave & 1;
    const int m0 = blockIdx.x * 128;
    const int n0 = blockIdx.y * 128;

    // staging: chunk p = r*256 + wave*64 + lane ; row = p>>2 ; kg swizzled
    int rowS[2], kgS[2];
#pragma unroll
    for (int r = 0; r < 2; ++r) {
        int p = r * 256 + wave * 64 + lane;
        rowS[r] = p >> 2;
        kgS[r]  = (p & 3) ^ ((rowS[r] >> 1) & 3);
    }

    f32x4 acc[4][4] = {};

    for (int k0 = 0; k0 < 1024; k0 += 32) {
#pragma unroll
        for (int r = 0; r < 2; ++r) {
            async_ld16(A  + (size_t)(m0 + rowS[r]) * 1024 + k0 + kgS[r] * 8,
                       As + (r * 256 + wave * 64) * 8);
            async_ld16(Bt + (size_t)(n0 + rowS[r]) * 1024 + k0 + kgS[r] * 8,
                       Bs + (r * 256 + wave * 64) * 8);
        }
        __syncthreads();

        bf16x8 af[4], bf[4];
#pragma unroll
        for (int mi = 0; mi < 4; ++mi) {
            int row = wm * 64 + mi * 16 + c;
            int pos = row * 4 + (quad ^ ((row >> 1) & 3));
            af[mi] = *(const bf16x8*)(As + pos * 8);
        }
#pragma unroll
        for (int ni = 0; ni < 4; ++ni) {
            int row = wn * 64 + ni * 16 + c;
            int pos = row * 4 + (quad ^ ((row >> 1) & 3));
            bf[ni] = *(const bf16x8*)(Bs + pos * 8);
        }
#pragma unroll
        for (int mi = 0; mi < 4; ++mi)
#pragma unroll
            for (int ni = 0; ni < 4; ++ni)
                acc[mi][ni] = __builtin_amdgcn_mfma_f32_16x16x32_bf16(
                    af[mi], bf[ni], acc[mi][ni], 0, 0, 0);
        __syncthreads();
    }

    if (MODE == 0) {
        const int which = n0 >> 10;
        short* __restrict__ outp = (which == 0) ? qo : (which == 1) ? ko : vo;
        const int nb = n0 & 1023;
#pragma unroll
        for (int mi = 0; mi < 4; ++mi) {
#pragma unroll
            for (int i = 0; i < 4; ++i) {
                const int m = m0 + wm * 64 + mi * 16 + quad * 4 + i;
                const int b = m >> 11, t = m & 2047;
#pragma unroll
                for (int ni = 0; ni < 4; ++ni) {
                    const int n = nb + wn * 64 + ni * 16 + c;
                    const int h = n >> 6, d = n & 63;
                    outp[(((size_t)b * H_ + h) * T_ + t) * D_ + d] =
                        f2bf(acc[mi][ni][i]);
                }
            }
        }
    } else {
#pragma unroll
        for (int mi = 0; mi < 4; ++mi) {
#pragma unroll
            for (int i = 0; i < 4; ++i) {
                const int m = m0 + wm * 64 + mi * 16 + quad * 4 + i;
#pragma unroll
                for (int ni = 0; ni < 4; ++ni) {
                    const int n = n0 + wn * 64 + ni * 16 + c;
                    Cout[(size_t)m * E_ + n] = acc[mi][ni][i] + bo[n];
                }
            }
        }
    }
}

// ---------------------------------------------------------------------------
// Flash attention with bf16 MFMA (round-2 kernel; epilogue now stores bf16).
// grid = (T/64, H, B), block 256.
// ---------------------------------------------------------------------------
#define VT_PITCH 48
#define P_PITCH  40

__global__ __launch_bounds__(256) void flash_attn(
        const short* __restrict__ q,
        const short* __restrict__ k,
        const short* __restrict__ v,
        const float* __restrict__ mask,
        short* __restrict__ attn) {
    const int h = blockIdx.y, b = blockIdx.z;
    const int t0 = (int)(gridDim.x - 1 - blockIdx.x) * 64;
    const int tid  = threadIdx.x;
    const int wave = tid >> 6, lane = tid & 63;
    const int c = lane & 15, quad = lane >> 4;

    __shared__ __align__(16) short VT[64 * VT_PITCH];
    __shared__ __align__(16) short Pb[4 * 16 * P_PITCH];

    const size_t bh = ((size_t)b * H_ + h) * T_;

    const int qrow = t0 + wave * 16 + c;
    const bf16x8 a0 = *(const bf16x8*)(q + (bh + qrow) * D_ + quad * 8);
    const bf16x8 a1 = *(const bf16x8*)(q + (bh + qrow) * D_ + 32 + quad * 8);

    f32x4 o0 = {0,0,0,0}, o1 = {0,0,0,0}, o2 = {0,0,0,0}, o3 = {0,0,0,0};
    float m_s[4] = {-INFINITY, -INFINITY, -INFINITY, -INFINITY};
    float l_s[4] = {0.f, 0.f, 0.f, 0.f};

    const int n_tiles = t0 / 32 + 2;
    const int vrow = tid >> 3;
    const int vd0  = (tid & 7) * 8;

    for (int it = 0; it < n_tiles; ++it) {
        const int s0 = it * 32;

        bf16x8 vv = *(const bf16x8*)(v + (bh + s0 + vrow) * D_ + vd0);
#pragma unroll
        for (int j = 0; j < 8; ++j)
            VT[(vd0 + j) * VT_PITCH + vrow] = vv[j];

        const bf16x8 bx0 = *(const bf16x8*)(k + (bh + s0 + c) * D_ + quad * 8);
        const bf16x8 bx1 = *(const bf16x8*)(k + (bh + s0 + c) * D_ + 32 + quad * 8);
        const bf16x8 by0 = *(const bf16x8*)(k + (bh + s0 + 16 + c) * D_ + quad * 8);
        const bf16x8 by1 = *(const bf16x8*)(k + (bh + s0 + 16 + c) * D_ + 32 + quad * 8);

        f32x4 sx = {0,0,0,0}, sy = {0,0,0,0};
        sx = __builtin_amdgcn_mfma_f32_16x16x32_bf16(a0, bx0, sx, 0, 0, 0);
        sx = __builtin_amdgcn_mfma_f32_16x16x32_bf16(a1, bx1, sx, 0, 0, 0);
        sy = __builtin_amdgcn_mfma_f32_16x16x32_bf16(a0, by0, sy, 0, 0, 0);
        sy = __builtin_amdgcn_mfma_f32_16x16x32_bf16(a1, by1, sy, 0, 0, 0);

        const float biasX = (1.0f - mask[(size_t)b * T_ + s0 + c])      * -3.402823466e38f;
        const float biasY = (1.0f - mask[(size_t)b * T_ + s0 + 16 + c]) * -3.402823466e38f;

        float pX[4], pY[4], alpha[4];
#pragma unroll
        for (int i = 0; i < 4; ++i) {
            const int tr = t0 + wave * 16 + quad * 4 + i;
            float vx = sx[i] * 0.125f + biasX;
            float vy = sy[i] * 0.125f + biasY;
            if (s0 + c > tr)      vx = -INFINITY;
            if (s0 + 16 + c > tr) vy = -INFINITY;
            float mx = fmaxf(vx, vy);
            mx = fmaxf(mx, __shfl_xor(mx, 1));
            mx = fmaxf(mx, __shfl_xor(mx, 2));
            mx = fmaxf(mx, __shfl_xor(mx, 4));
            mx = fmaxf(mx, __shfl_xor(mx, 8));
            const float mnew = fmaxf(m_s[i], mx);
            const float cm   = fmaxf(mnew, -1e30f);
            alpha[i] = __expf(fmaxf(m_s[i], -1e30f) - cm);
            m_s[i] = mnew;
            const float ex = __expf(vx - cm);
            const float ey = __expf(vy - cm);
            pX[i] = ex; pY[i] = ey;
            float rs = ex + ey;
            rs += __shfl_xor(rs, 1);
            rs += __shfl_xor(rs, 2);
            rs += __shfl_xor(rs, 4);
            rs += __shfl_xor(rs, 8);
            l_s[i] = l_s[i] * alpha[i] + rs;
        }
#pragma unroll
        for (int i = 0; i < 4; ++i) {
            o0[i] *= alpha[i]; o1[i] *= alpha[i];
            o2[i] *= alpha[i]; o3[i] *= alpha[i];
        }

        short* P = Pb + wave * 16 * P_PITCH;
#pragma unroll
        for (int i = 0; i < 4; ++i) {
            P[(quad * 4 + i) * P_PITCH + c]      = f2bf(pX[i]);
            P[(quad * 4 + i) * P_PITCH + 16 + c] = f2bf(pY[i]);
        }

        __syncthreads();

        const bf16x8 pf  = *(const bf16x8*)(P + c * P_PITCH + quad * 8);
        const bf16x8 v0f = *(const bf16x8*)(&VT[(0*16 + c) * VT_PITCH + quad * 8]);
        const bf16x8 v1f = *(const bf16x8*)(&VT[(1*16 + c) * VT_PITCH + quad * 8]);
        const bf16x8 v2f = *(const bf16x8*)(&VT[(2*16 + c) * VT_PITCH + quad * 8]);
        const bf16x8 v3f = *(const bf16x8*)(&VT[(3*16 + c) * VT_PITCH + quad * 8]);

        o0 = __builtin_amdgcn_mfma_f32_16x16x32_bf16(pf, v0f, o0, 0, 0, 0);
        o1 = __builtin_amdgcn_mfma_f32_16x16x32_bf16(pf, v1f, o1, 0, 0, 0);
        o2 = __builtin_amdgcn_mfma_f32_16x16x32_bf16(pf, v2f, o2, 0, 0, 0);
        o3 = __builtin_amdgcn_mfma_f32_16x16x32_bf16(pf, v3f, o3, 0, 0, 0);

        __syncthreads();
    }

#pragma unroll
    for (int i = 0; i < 4; ++i) {
        const int t = t0 + wave * 16 + quad * 4 + i;
        const float invl = 1.0f / l_s[i];
        const size_t base = ((size_t)b * T_ + t) * E_ + h * D_;
        attn[base + 0*16 + c] = f2bf(o0[i] * invl);
        attn[base + 1*16 + c] = f2bf(o1[i] * invl);
        attn[base + 2*16 + c] = f2bf(o2[i] * invl);
        attn[base + 3*16 + c] = f2bf(o3[i] * invl);
    }
}

// ---------------------------------------------------------------------------
extern "C" void kernel_launch(void* const* d_in, const int* in_sizes, int n_in,
                              void* d_out, int out_size, void* d_ws, size_t ws_size,
                              hipStream_t stream) {
    const float* x    = (const float*)d_in[0];
    const float* mask = (const float*)d_in[1];
    const float* Wq   = (const float*)d_in[2];
    const float* Wk   = (const float*)d_in[3];
    const float* Wv   = (const float*)d_in[4];
    const float* Wo   = (const float*)d_in[5];
    const float* bo   = (const float*)d_in[6];
    float* out        = (float*)d_out;

    const size_t S = (size_t)M_ * E_;              // 8.4M elems
    char* ws = (char*)d_ws;
    short* xb  = (short*)ws;                       // bf16 x; later aliased as attn
    short* qb  = (short*)(ws + S * 2);
    short* kb  = (short*)(ws + S * 4);
    short* vb  = (short*)(ws + S * 6);
    short* Wt  = (short*)(ws + S * 8);             // [3*1024][1024] bf16
    short* Wob = (short*)(ws + S * 8 + (size_t)3 * 1024 * 1024 * 2);
    short* attnb = xb;                             // alias: xb dead after qkv GEMM

    conv_bf16<<<dim3(M_ * E_ / 1024), 256, 0, stream>>>(x, xb);
    conv_bf16<<<dim3(E_ * E_ / 1024), 256, 0, stream>>>(Wo, Wob);
    wtrans<<<dim3(E_ / 64, H_, 3), 256, 0, stream>>>(Wq, Wk, Wv, Wt);

    mfma_gemm<0><<<dim3(M_ / 128, 3 * E_ / 128), 256, 0, stream>>>(
        xb, Wt, qb, kb, vb, nullptr, nullptr);

    flash_attn<<<dim3(T_ / 64, H_, B_), 256, 0, stream>>>(qb, kb, vb, mask, attnb);

    mfma_gemm<1><<<dim3(M_ / 128, E_ / 128), 256, 0, stream>>>(
        attnb, Wob, nullptr, nullptr, nullptr, out, bo);
}

// Round 4
// 311.567 us; speedup vs baseline: 19.8121x; 1.7856x over previous
//
#include <hip/hip_runtime.h>
#include <hip/hip_bf16.h>

#define B_ 4
#define T_ 2048
#define E_ 1024
#define H_ 16
#define D_ 64
#define M_ (B_*T_)   // 8192 rows

typedef short bf16x8 __attribute__((ext_vector_type(8)));
typedef float f32x4  __attribute__((ext_vector_type(4)));

__device__ __forceinline__ short f2bf(float f) {
    __hip_bfloat16 h = __float2bfloat16(f);
    return *reinterpret_cast<short*>(&h);
}

// round-half-up fp32->bf16 pack of two values into a u32
__device__ __forceinline__ unsigned int pk2(float a, float b) {
    unsigned int ua = __float_as_uint(a), ub = __float_as_uint(b);
    return ((ua + 0x8000u) >> 16) | ((ub + 0x8000u) & 0xffff0000u);
}

__device__ __forceinline__ void async_ld16(const void* g, void* l) {
    __builtin_amdgcn_global_load_lds(
        (const __attribute__((address_space(1))) unsigned int*)g,
        (__attribute__((address_space(3))) unsigned int*)l, 16, 0, 0);
}

// ---------------------------------------------------------------------------
// Prep: fp32 -> bf16 elementwise (x and Wo).
// ---------------------------------------------------------------------------
__global__ void conv_bf16(const float* __restrict__ src, short* __restrict__ dst) {
    const int i = blockIdx.x * 256 + threadIdx.x;
    float4 v = ((const float4*)src)[i];
    short4 o = make_short4(f2bf(v.x), f2bf(v.y), f2bf(v.z), f2bf(v.w));
    ((short4*)dst)[i] = o;
}

// ---------------------------------------------------------------------------
// Prep: bias_pre[b][s] = ((1-mask)*(-3.4e38)) * 1.4427 - 6*1.4427
// (exp2-folded additive bias with static max m=6). mask=1 -> -8.6565.
// ---------------------------------------------------------------------------
__global__ void bias_prep(const float* __restrict__ mask, float* __restrict__ bias) {
    const int i = blockIdx.x * 256 + threadIdx.x;
    float bm = (1.0f - mask[i]) * -3.402823466e38f;   // 0 or -3.4e38
    bias[i] = fmaf(bm, 1.4426950f, -8.6561700f);      // -inf ok (exp2 -> 0)
}

// ---------------------------------------------------------------------------
// Prep: Wq/Wk/Wv [H][E][D] fp32 -> Wt [3*1024 n][1024 e] bf16, n = h*64+d.
// ---------------------------------------------------------------------------
__global__ void wtrans(const float* __restrict__ Wq,
                       const float* __restrict__ Wk,
                       const float* __restrict__ Wv,
                       short* __restrict__ Wt) {
    const int which = blockIdx.z;
    const float* __restrict__ W = (which == 0) ? Wq : (which == 1) ? Wk : Wv;
    const int h  = blockIdx.y;
    const int e0 = blockIdx.x * 64;

    __shared__ float tile[64][65];
    const int tid = threadIdx.x;

#pragma unroll
    for (int r = 0; r < 4; ++r) {
        int lin = tid + r * 256;
        int er = lin >> 4, c4 = (lin & 15) * 4;
        float4 v = *(const float4*)(W + ((size_t)h * E_ + e0 + er) * D_ + c4);
        tile[er][c4 + 0] = v.x; tile[er][c4 + 1] = v.y;
        tile[er][c4 + 2] = v.z; tile[er][c4 + 3] = v.w;
    }
    __syncthreads();
#pragma unroll
    for (int r = 0; r < 4; ++r) {
        int lin = tid + r * 256;
        int dr = lin >> 4, j4 = (lin & 15) * 4;
        short4 o = make_short4(f2bf(tile[j4 + 0][dr]), f2bf(tile[j4 + 1][dr]),
                               f2bf(tile[j4 + 2][dr]), f2bf(tile[j4 + 3][dr]));
        *(short4*)(Wt + ((size_t)which * 1024 + h * 64 + dr) * E_ + e0 + j4) = o;
    }
}

// ---------------------------------------------------------------------------
// Prep: V [b,h,t,d] bf16 -> Vt [b,h,d,t] bf16 (64x64 LDS tile transpose).
// grid (T/64, H, B), block 256.
// ---------------------------------------------------------------------------
__global__ void vtrans(const short* __restrict__ v, short* __restrict__ vt) {
    const int h = blockIdx.y, b = blockIdx.z;
    const int t0 = blockIdx.x * 64;
    const int tid = threadIdx.x;
    const size_t bh = ((size_t)b * H_ + h);

    __shared__ short tl[64 * 72];   // [d][t], pitch 72 shorts = 144B (16B-mult)

    const int tt = tid >> 2, dc = (tid & 3) * 16;
#pragma unroll
    for (int g = 0; g < 2; ++g) {
        bf16x8 vv = *(const bf16x8*)(v + (bh * T_ + t0 + tt) * D_ + dc + g * 8);
#pragma unroll
        for (int j = 0; j < 8; ++j)
            tl[(dc + g * 8 + j) * 72 + tt] = vv[j];
    }
    __syncthreads();
    const int dd = tid >> 2, tc = (tid & 3) * 16;
#pragma unroll
    for (int g = 0; g < 2; ++g) {
        bf16x8 rd = *(const bf16x8*)(tl + dd * 72 + tc + g * 8);
        *(bf16x8*)(vt + (bh * D_ + dd) * T_ + t0 + tc + g * 8) = rd;
    }
}

// ---------------------------------------------------------------------------
// MFMA GEMM (m97 structure), unchanged from round 3.
// MODE 0: C -> q/k/v bf16 [B,H,T,D] scatter.  MODE 1: C -> fp32 [M][E] + bias.
// ---------------------------------------------------------------------------
template <int MODE>
__global__ __launch_bounds__(256) void mfma_gemm(
        const short* __restrict__ A,
        const short* __restrict__ Bt,
        short* __restrict__ qo, short* __restrict__ ko, short* __restrict__ vo,
        float* __restrict__ Cout, const float* __restrict__ bo) {
    __shared__ __align__(16) short As[128 * 32];
    __shared__ __align__(16) short Bs[128 * 32];

    const int tid  = threadIdx.x;
    const int wave = tid >> 6, lane = tid & 63;
    const int c = lane & 15, quad = lane >> 4;
    const int wm = wave >> 1, wn = wave & 1;
    const int m0 = blockIdx.x * 128;
    const int n0 = blockIdx.y * 128;

    int rowS[2], kgS[2];
#pragma unroll
    for (int r = 0; r < 2; ++r) {
        int p = r * 256 + wave * 64 + lane;
        rowS[r] = p >> 2;
        kgS[r]  = (p & 3) ^ ((rowS[r] >> 1) & 3);
    }

    f32x4 acc[4][4] = {};

    for (int k0 = 0; k0 < 1024; k0 += 32) {
#pragma unroll
        for (int r = 0; r < 2; ++r) {
            async_ld16(A  + (size_t)(m0 + rowS[r]) * 1024 + k0 + kgS[r] * 8,
                       As + (r * 256 + wave * 64) * 8);
            async_ld16(Bt + (size_t)(n0 + rowS[r]) * 1024 + k0 + kgS[r] * 8,
                       Bs + (r * 256 + wave * 64) * 8);
        }
        __syncthreads();

        bf16x8 af[4], bf[4];
#pragma unroll
        for (int mi = 0; mi < 4; ++mi) {
            int row = wm * 64 + mi * 16 + c;
            int pos = row * 4 + (quad ^ ((row >> 1) & 3));
            af[mi] = *(const bf16x8*)(As + pos * 8);
        }
#pragma unroll
        for (int ni = 0; ni < 4; ++ni) {
            int row = wn * 64 + ni * 16 + c;
            int pos = row * 4 + (quad ^ ((row >> 1) & 3));
            bf[ni] = *(const bf16x8*)(Bs + pos * 8);
        }
#pragma unroll
        for (int mi = 0; mi < 4; ++mi)
#pragma unroll
            for (int ni = 0; ni < 4; ++ni)
                acc[mi][ni] = __builtin_amdgcn_mfma_f32_16x16x32_bf16(
                    af[mi], bf[ni], acc[mi][ni], 0, 0, 0);
        __syncthreads();
    }

    if (MODE == 0) {
        const int which = n0 >> 10;
        short* __restrict__ outp = (which == 0) ? qo : (which == 1) ? ko : vo;
        const int nb = n0 & 1023;
#pragma unroll
        for (int mi = 0; mi < 4; ++mi) {
#pragma unroll
            for (int i = 0; i < 4; ++i) {
                const int m = m0 + wm * 64 + mi * 16 + quad * 4 + i;
                const int b = m >> 11, t = m & 2047;
#pragma unroll
                for (int ni = 0; ni < 4; ++ni) {
                    const int n = nb + wn * 64 + ni * 16 + c;
                    const int h = n >> 6, d = n & 63;
                    outp[(((size_t)b * H_ + h) * T_ + t) * D_ + d] =
                        f2bf(acc[mi][ni][i]);
                }
            }
        }
    } else {
#pragma unroll
        for (int mi = 0; mi < 4; ++mi) {
#pragma unroll
            for (int i = 0; i < 4; ++i) {
                const int m = m0 + wm * 64 + mi * 16 + quad * 4 + i;
#pragma unroll
                for (int ni = 0; ni < 4; ++ni) {
                    const int n = n0 + wn * 64 + ni * 16 + c;
                    Cout[(size_t)m * E_ + n] = acc[mi][ni][i] + bo[n];
                }
            }
        }
    }
}

// ---------------------------------------------------------------------------
// Flash attention v2: barrier-free fat waves, S^T/O^T formulation, static max.
// grid (H, B, 8), block 256 (4 waves). Wave w of group z owns idx = z*4+w:
// rows [32*idx, +32) (subs 0,1) and [2048-32*(idx+1), +32) (subs 2,3) --
// perfectly uniform work, one shared K/Vt stream per wave.
//   S^T = K·Q^T  (C: col=lane&15=q, row=quad*4+i=s)
//   O^T = V^T·P^T; l via ones-row MFMA.  P^T via per-wave LDS (no barriers).
// ---------------------------------------------------------------------------
__global__ __launch_bounds__(256, 2) void flash_attn2(
        const short* __restrict__ qg,
        const short* __restrict__ kg,
        const short* __restrict__ vtg,
        const float* __restrict__ biasg,
        short* __restrict__ attn) {
    const int h = blockIdx.x, b = blockIdx.y;
    const int tid  = threadIdx.x;
    const int wave = tid >> 6, lane = tid & 63;
    const int c = lane & 15, quad = lane >> 4;
    const int idx = blockIdx.z * 4 + wave;            // 0..31
    const int ql0 = idx * 32;
    const int qh0 = T_ - 32 * (idx + 1);

    __shared__ __align__(16) short Plds[4][2048];     // 4KB per wave
    char* lp = (char*)&Plds[wave][0];

    const size_t bh = ((size_t)b * H_ + h);
    const short* qb  = qg  + bh * T_ * D_;
    const short* kb  = kg  + bh * T_ * D_;
    const short* vtb = vtg + bh * D_ * T_;
    const float* biasb = biasg + (size_t)b * T_;

    // P LDS addresses (constant across tiles). Row q_loc = sub*16+c, 64B.
    // logical 16B pair L (s-range L*8..L*8+7), phys = L ^ (c&3).
    int pwx[4], pwy[4], pr[4];
#pragma unroll
    for (int sub = 0; sub < 4; ++sub) {
        int rowb = (sub * 16 + c) * 64;
        pwx[sub] = rowb + ((((quad >> 1)    ) ^ (c & 3)) << 4) + ((quad & 1) << 3);
        pwy[sub] = rowb + (((((quad >> 1)+2) ^ (c & 3)) & 3) << 4) + ((quad & 1) << 3);
        pr[sub]  = rowb + ((quad ^ (c & 3)) << 4);
    }

    // Q fragments (B operand of S^T): value Q[qrow][d=half*32+quad*8+j]
    bf16x8 qf[4][2];
#pragma unroll
    for (int sub = 0; sub < 4; ++sub) {
        int qrow = (sub < 2) ? (ql0 + sub * 16 + c) : (qh0 + (sub - 2) * 16 + c);
#pragma unroll
        for (int half = 0; half < 2; ++half)
            qf[sub][half] = *(const bf16x8*)(qb + (size_t)qrow * D_ + half * 32 + quad * 8);
    }

    // ones A-fragment for l-row MFMA: row m=0 is ones, others zero
    bf16x8 onesf = {0,0,0,0,0,0,0,0};
    if (c == 0) {
        const short one = 0x3F80;
        onesf = (bf16x8){one,one,one,one,one,one,one,one};
    }

    f32x4 o[4][4] = {};     // [dt][sub]  O^T accum
    f32x4 lacc[4] = {};     // l in (quad0, reg0)

    // mcase: 0 none, 1 mask subs 0,1 (diag-low), 2 mask subs 2,3 (diag-high)
    auto do_tile = [&](int s0, int sbeg, int mcase) {
        // K A-fragments: K[s0+kst*16+c][half*32+quad*8+j]
        bf16x8 ka[2][2];
#pragma unroll
        for (int kst = 0; kst < 2; ++kst)
#pragma unroll
            for (int half = 0; half < 2; ++half)
                ka[kst][half] = *(const bf16x8*)(kb + (size_t)(s0 + kst * 16 + c) * D_
                                                 + half * 32 + quad * 8);
        float4 bx4 = *(const float4*)(biasb + s0 + quad * 4);
        float4 by4 = *(const float4*)(biasb + s0 + 16 + quad * 4);
        const float bx[4] = {bx4.x, bx4.y, bx4.z, bx4.w};
        const float by[4] = {by4.x, by4.y, by4.z, by4.w};

#pragma unroll
        for (int sub = 0; sub < 4; ++sub) {
            if (sub < sbeg) continue;
            f32x4 sx = {0,0,0,0}, sy = {0,0,0,0};
            sx = __builtin_amdgcn_mfma_f32_16x16x32_bf16(ka[0][0], qf[sub][0], sx, 0,0,0);
            sx = __builtin_amdgcn_mfma_f32_16x16x32_bf16(ka[0][1], qf[sub][1], sx, 0,0,0);
            sy = __builtin_amdgcn_mfma_f32_16x16x32_bf16(ka[1][0], qf[sub][0], sy, 0,0,0);
            sy = __builtin_amdgcn_mfma_f32_16x16x32_bf16(ka[1][1], qf[sub][1], sy, 0,0,0);

            float px[4], py[4];
#pragma unroll
            for (int i = 0; i < 4; ++i) {
                px[i] = __builtin_amdgcn_exp2f(fmaf(sx[i], 0.18033688f, bx[i]));
                py[i] = __builtin_amdgcn_exp2f(fmaf(sy[i], 0.18033688f, by[i]));
            }
            const bool msk = (mcase == 1 && sub < 2) || (mcase == 2 && sub >= 2);
            if (msk) {
                const int qq = (sub & 1) * 16 + c;     // q - qbase (s0 == qbase)
#pragma unroll
                for (int i = 0; i < 4; ++i) {
                    if (quad * 4 + i      > qq) px[i] = 0.0f;
                    if (16 + quad * 4 + i > qq) py[i] = 0.0f;
                }
            }
            *(unsigned int*)(lp + pwx[sub])     = pk2(px[0], px[1]);
            *(unsigned int*)(lp + pwx[sub] + 4) = pk2(px[2], px[3]);
            *(unsigned int*)(lp + pwy[sub])     = pk2(py[0], py[1]);
            *(unsigned int*)(lp + pwy[sub] + 4) = pk2(py[2], py[3]);
        }

        // Vt A-fragments: Vt[dt*16+c][s0+quad*8+j]
        bf16x8 va[4];
#pragma unroll
        for (int dt = 0; dt < 4; ++dt)
            va[dt] = *(const bf16x8*)(vtb + (size_t)(dt * 16 + c) * T_ + s0 + quad * 8);

#pragma unroll
        for (int sub = 0; sub < 4; ++sub) {
            if (sub < sbeg) continue;
            bf16x8 pf = *(const bf16x8*)(lp + pr[sub]);
#pragma unroll
            for (int dt = 0; dt < 4; ++dt)
                o[dt][sub] = __builtin_amdgcn_mfma_f32_16x16x32_bf16(
                    va[dt], pf, o[dt][sub], 0, 0, 0);
            lacc[sub] = __builtin_amdgcn_mfma_f32_16x16x32_bf16(
                onesf, pf, lacc[sub], 0, 0, 0);
        }
    };

    int s0 = 0;
    for (int it = 0; it < idx; ++it, s0 += 32) do_tile(s0, 0, 0);
    do_tile(s0, 0, 1); s0 += 32;                       // diag of low rows
    const int nb = 62 - 2 * idx;
    for (int it = 0; it < nb; ++it, s0 += 32) do_tile(s0, 2, 0);
    do_tile(s0, 2, 2);                                 // diag of high rows

    // ---- epilogue: normalize, transpose via own LDS region, store bf16 ----
    float inv[4];
#pragma unroll
    for (int sub = 0; sub < 4; ++sub)
        inv[sub] = 1.0f / __shfl(lacc[sub][0], c, 64);

    const int t_row = (lane < 32) ? (ql0 + lane) : (qh0 + lane - 32);
    short* ab = attn + ((size_t)b * T_) * E_ + h * D_;

#pragma unroll
    for (int h2 = 0; h2 < 2; ++h2) {
#pragma unroll
        for (int dt2 = 0; dt2 < 2; ++dt2) {
            const int dt = h2 * 2 + dt2;
            const int g = dt2 * 2 + (quad >> 1);       // 16B granule in 64B row
#pragma unroll
            for (int sub = 0; sub < 4; ++sub) {
                const int addr = (sub * 16 + c) * 64 + ((g ^ (c & 3)) << 4)
                               + ((quad & 1) << 3);
                *(unsigned int*)(lp + addr)     = pk2(o[dt][sub][0] * inv[sub],
                                                      o[dt][sub][1] * inv[sub]);
                *(unsigned int*)(lp + addr + 4) = pk2(o[dt][sub][2] * inv[sub],
                                                      o[dt][sub][3] * inv[sub]);
            }
        }
#pragma unroll
        for (int e = 0; e < 4; ++e) {
            bf16x8 rd = *(const bf16x8*)(lp + lane * 64 + ((e ^ (lane & 3)) << 4));
            *(bf16x8*)(ab + (size_t)t_row * E_ + h2 * 32 + e * 8) = rd;
        }
    }
}

// ---------------------------------------------------------------------------
extern "C" void kernel_launch(void* const* d_in, const int* in_sizes, int n_in,
                              void* d_out, int out_size, void* d_ws, size_t ws_size,
                              hipStream_t stream) {
    const float* x    = (const float*)d_in[0];
    const float* mask = (const float*)d_in[1];
    const float* Wq   = (const float*)d_in[2];
    const float* Wk   = (const float*)d_in[3];
    const float* Wv   = (const float*)d_in[4];
    const float* Wo   = (const float*)d_in[5];
    const float* bo   = (const float*)d_in[6];
    float* out        = (float*)d_out;

    const size_t S = (size_t)M_ * E_;              // 8.4M elems
    char* ws = (char*)d_ws;
    short* xb  = (short*)ws;                       // bf16 x; reused as Vt after MODE0
    short* qb  = (short*)(ws + S * 2);
    short* kb  = (short*)(ws + S * 4);
    short* vb  = (short*)(ws + S * 6);             // reused as attn after vtrans
    short* Wt  = (short*)(ws + S * 8);
    short* Wob = (short*)(ws + S * 8 + (size_t)3 * 1024 * 1024 * 2);
    float* bias = (float*)(ws + S * 8 + (size_t)4 * 1024 * 1024 * 2);
    short* vt    = xb;
    short* attnb = vb;

    conv_bf16<<<dim3(M_ * E_ / 1024), 256, 0, stream>>>(x, xb);
    conv_bf16<<<dim3(E_ * E_ / 1024), 256, 0, stream>>>(Wo, Wob);
    wtrans<<<dim3(E_ / 64, H_, 3), 256, 0, stream>>>(Wq, Wk, Wv, Wt);
    bias_prep<<<dim3(B_ * T_ / 256), 256, 0, stream>>>(mask, bias);

    mfma_gemm<0><<<dim3(M_ / 128, 3 * E_ / 128), 256, 0, stream>>>(
        xb, Wt, qb, kb, vb, nullptr, nullptr);

    vtrans<<<dim3(T_ / 64, H_, B_), 256, 0, stream>>>(vb, vt);

    flash_attn2<<<dim3(H_, B_, 8), 256, 0, stream>>>(qb, kb, vt, bias, attnb);

    mfma_gemm<1><<<dim3(M_ / 128, E_ / 128), 256, 0, stream>>>(
        attnb, Wob, nullptr, nullptr, nullptr, out, bo);
}

// Round 6
// 311.470 us; speedup vs baseline: 19.8183x; 1.0003x over previous
//
#include <hip/hip_runtime.h>
#include <hip/hip_bf16.h>

#define B_ 4
#define T_ 2048
#define E_ 1024
#define H_ 16
#define D_ 64
#define M_ (B_*T_)   // 8192 rows

typedef short bf16x8 __attribute__((ext_vector_type(8)));
typedef float f32x4  __attribute__((ext_vector_type(4)));

__device__ __forceinline__ short f2bf(float f) {
    __hip_bfloat16 h = __float2bfloat16(f);
    return *reinterpret_cast<short*>(&h);
}

// round-half-up fp32->bf16 pack of two values into a u32
__device__ __forceinline__ unsigned int pk2(float a, float b) {
    unsigned int ua = __float_as_uint(a), ub = __float_as_uint(b);
    return ((ua + 0x8000u) >> 16) | ((ub + 0x8000u) & 0xffff0000u);
}

__device__ __forceinline__ void async_ld16(const void* g, void* l) {
    __builtin_amdgcn_global_load_lds(
        (const __attribute__((address_space(1))) unsigned int*)g,
        (__attribute__((address_space(3))) unsigned int*)l, 16, 0, 0);
}

// ---------------------------------------------------------------------------
// Prep: fp32 -> bf16 elementwise (x and Wo).
// ---------------------------------------------------------------------------
__global__ void conv_bf16(const float* __restrict__ src, short* __restrict__ dst) {
    const int i = blockIdx.x * 256 + threadIdx.x;
    float4 v = ((const float4*)src)[i];
    short4 o = make_short4(f2bf(v.x), f2bf(v.y), f2bf(v.z), f2bf(v.w));
    ((short4*)dst)[i] = o;
}

// ---------------------------------------------------------------------------
// Prep: bias_pre[b][s] = ((1-mask)*(-3.4e38)) * 1.4427 - 6*1.4427
// (exp2-folded additive bias with static max m=6). mask=1 -> -8.6565.
// ---------------------------------------------------------------------------
__global__ void bias_prep(const float* __restrict__ mask, float* __restrict__ bias) {
    const int i = blockIdx.x * 256 + threadIdx.x;
    float bm = (1.0f - mask[i]) * -3.402823466e38f;   // 0 or -3.4e38
    bias[i] = fmaf(bm, 1.4426950f, -8.6561700f);      // -inf ok (exp2 -> 0)
}

// ---------------------------------------------------------------------------
// Prep: Wq/Wk/Wv [H][E][D] fp32 -> Wt [3*1024 n][1024 e] bf16, n = h*64+d.
// ---------------------------------------------------------------------------
__global__ void wtrans(const float* __restrict__ Wq,
                       const float* __restrict__ Wk,
                       const float* __restrict__ Wv,
                       short* __restrict__ Wt) {
    const int which = blockIdx.z;
    const float* __restrict__ W = (which == 0) ? Wq : (which == 1) ? Wk : Wv;
    const int h  = blockIdx.y;
    const int e0 = blockIdx.x * 64;

    __shared__ float tile[64][65];
    const int tid = threadIdx.x;

#pragma unroll
    for (int r = 0; r < 4; ++r) {
        int lin = tid + r * 256;
        int er = lin >> 4, c4 = (lin & 15) * 4;
        float4 v = *(const float4*)(W + ((size_t)h * E_ + e0 + er) * D_ + c4);
        tile[er][c4 + 0] = v.x; tile[er][c4 + 1] = v.y;
        tile[er][c4 + 2] = v.z; tile[er][c4 + 3] = v.w;
    }
    __syncthreads();
#pragma unroll
    for (int r = 0; r < 4; ++r) {
        int lin = tid + r * 256;
        int dr = lin >> 4, j4 = (lin & 15) * 4;
        short4 o = make_short4(f2bf(tile[j4 + 0][dr]), f2bf(tile[j4 + 1][dr]),
                               f2bf(tile[j4 + 2][dr]), f2bf(tile[j4 + 3][dr]));
        *(short4*)(Wt + ((size_t)which * 1024 + h * 64 + dr) * E_ + e0 + j4) = o;
    }
}

// ---------------------------------------------------------------------------
// MFMA GEMM (m97 structure).
// MODE 0: C -> q/k bf16 [B,H,T,D] scatter; V directly TRANSPOSED [B,H,D,T]
//         (short4 along t: regs i = 4 consecutive t at fixed d).
// MODE 1: C -> fp32 [M][E] + bias.
// ---------------------------------------------------------------------------
template <int MODE>
__global__ __launch_bounds__(256) void mfma_gemm(
        const short* __restrict__ A,
        const short* __restrict__ Bt,
        short* __restrict__ qo, short* __restrict__ ko, short* __restrict__ vo,
        float* __restrict__ Cout, const float* __restrict__ bo) {
    __shared__ __align__(16) short As[128 * 32];
    __shared__ __align__(16) short Bs[128 * 32];

    const int tid  = threadIdx.x;
    const int wave = tid >> 6, lane = tid & 63;
    const int c = lane & 15, quad = lane >> 4;
    const int wm = wave >> 1, wn = wave & 1;
    const int m0 = blockIdx.x * 128;
    const int n0 = blockIdx.y * 128;

    int rowS[2], kgS[2];
#pragma unroll
    for (int r = 0; r < 2; ++r) {
        int p = r * 256 + wave * 64 + lane;
        rowS[r] = p >> 2;
        kgS[r]  = (p & 3) ^ ((rowS[r] >> 1) & 3);
    }

    f32x4 acc[4][4] = {};

    for (int k0 = 0; k0 < 1024; k0 += 32) {
#pragma unroll
        for (int r = 0; r < 2; ++r) {
            async_ld16(A  + (size_t)(m0 + rowS[r]) * 1024 + k0 + kgS[r] * 8,
                       As + (r * 256 + wave * 64) * 8);
            async_ld16(Bt + (size_t)(n0 + rowS[r]) * 1024 + k0 + kgS[r] * 8,
                       Bs + (r * 256 + wave * 64) * 8);
        }
        __syncthreads();

        bf16x8 af[4], bf[4];
#pragma unroll
        for (int mi = 0; mi < 4; ++mi) {
            int row = wm * 64 + mi * 16 + c;
            int pos = row * 4 + (quad ^ ((row >> 1) & 3));
            af[mi] = *(const bf16x8*)(As + pos * 8);
        }
#pragma unroll
        for (int ni = 0; ni < 4; ++ni) {
            int row = wn * 64 + ni * 16 + c;
            int pos = row * 4 + (quad ^ ((row >> 1) & 3));
            bf[ni] = *(const bf16x8*)(Bs + pos * 8);
        }
#pragma unroll
        for (int mi = 0; mi < 4; ++mi)
#pragma unroll
            for (int ni = 0; ni < 4; ++ni)
                acc[mi][ni] = __builtin_amdgcn_mfma_f32_16x16x32_bf16(
                    af[mi], bf[ni], acc[mi][ni], 0, 0, 0);
        __syncthreads();
    }

    if (MODE == 0) {
        const int which = n0 >> 10;
        const int nb = n0 & 1023;
        if (which == 2) {
            // V: store transposed [b,h,d,t], vectorized short4 along t
#pragma unroll
            for (int mi = 0; mi < 4; ++mi) {
                const int m = m0 + wm * 64 + mi * 16 + quad * 4;
                const int b = m >> 11, t = m & 2047;
#pragma unroll
                for (int ni = 0; ni < 4; ++ni) {
                    const int n = nb + wn * 64 + ni * 16 + c;
                    const int h = n >> 6, d = n & 63;
                    short4 s4 = make_short4(f2bf(acc[mi][ni][0]), f2bf(acc[mi][ni][1]),
                                            f2bf(acc[mi][ni][2]), f2bf(acc[mi][ni][3]));
                    *(short4*)(vo + (((size_t)b * H_ + h) * D_ + d) * T_ + t) = s4;
                }
            }
        } else {
            short* __restrict__ outp = (which == 0) ? qo : ko;
#pragma unroll
            for (int mi = 0; mi < 4; ++mi) {
#pragma unroll
                for (int i = 0; i < 4; ++i) {
                    const int m = m0 + wm * 64 + mi * 16 + quad * 4 + i;
                    const int b = m >> 11, t = m & 2047;
#pragma unroll
                    for (int ni = 0; ni < 4; ++ni) {
                        const int n = nb + wn * 64 + ni * 16 + c;
                        const int h = n >> 6, d = n & 63;
                        outp[(((size_t)b * H_ + h) * T_ + t) * D_ + d] =
                            f2bf(acc[mi][ni][i]);
                    }
                }
            }
        }
    } else {
#pragma unroll
        for (int mi = 0; mi < 4; ++mi) {
#pragma unroll
            for (int i = 0; i < 4; ++i) {
                const int m = m0 + wm * 64 + mi * 16 + quad * 4 + i;
#pragma unroll
                for (int ni = 0; ni < 4; ++ni) {
                    const int n = n0 + wn * 64 + ni * 16 + c;
                    Cout[(size_t)m * E_ + n] = acc[mi][ni][i] + bo[n];
                }
            }
        }
    }
}

// ---------------------------------------------------------------------------
// Flash attention v3 (fixed): split-s across the 4 waves of a block.
// grid (H, B, 32), block 256. Block owns idx = blockIdx.z:
//   q rows [32*idx, +32) (subs 0,1) and [32*(63-idx), +32) (subs 2,3).
// Wave w handles key tiles {w, w+4, ...}. Static max (m=6, exp2-folded)
// makes partials linear: block merge = 4 f32 add rounds in LDS.
//   S^T = K·Q^T;  O^T = V^T·P^T;  l via ones-row MFMA.
// o[dt][sub][i] = O^T[d = dt*16+quad*4+i][q = sub*16+c]  (C: col=q, row=d).
// Merge buffer is Ob[q][d] pitch 72 floats -> f32x4 along i (consecutive d).
// ---------------------------------------------------------------------------
__global__ __launch_bounds__(256) void flash_attn3(
        const short* __restrict__ qg,
        const short* __restrict__ kg,
        const short* __restrict__ vtg,
        const float* __restrict__ biasg,
        short* __restrict__ attn) {
    const int h = blockIdx.x, b = blockIdx.y;
    const int idx = blockIdx.z;                    // 0..31
    const int tid  = threadIdx.x;
    const int wave = tid >> 6, lane = tid & 63;
    const int c = lane & 15, quad = lane >> 4;
    const int ql0 = idx * 32;
    const int qh0 = (63 - idx) * 32;

    // P: per wave 64 rows x 80B = 5120B; total 20480B. Reused for merge.
    __shared__ __align__(16) char Plds[20480];
    char* lp = Plds + wave * 5120;

    const size_t bh = (size_t)b * H_ + h;
    const short* qb  = qg  + bh * (size_t)T_ * D_;
    const short* kb  = kg  + bh * (size_t)T_ * D_;
    const short* vtb = vtg + bh * (size_t)D_ * T_;
    const float* biasb = biasg + (size_t)b * T_;

    int rw[4];
#pragma unroll
    for (int sub = 0; sub < 4; ++sub) rw[sub] = (sub * 16 + c) * 80;

    // Q fragments (B operand of S^T)
    bf16x8 qf[4][2];
#pragma unroll
    for (int sub = 0; sub < 4; ++sub) {
        int qrow = ((sub < 2) ? (ql0 + sub * 16) : (qh0 + (sub - 2) * 16)) + c;
#pragma unroll
        for (int half = 0; half < 2; ++half)
            qf[sub][half] = *(const bf16x8*)(qb + (size_t)qrow * D_ + half * 32 + quad * 8);
    }

    // ones A-fragment (row m=0) for l-row MFMA
    bf16x8 onesf = {0,0,0,0,0,0,0,0};
    if (c == 0) {
        const short one = 0x3F80;
        onesf = (bf16x8){one,one,one,one,one,one,one,one};
    }

    f32x4 o[4][4] = {};     // [dt][sub]
    f32x4 lacc[4] = {};

    const int tmax = 63 - idx;                     // last key tile (inclusive)
    for (int tt = wave; tt <= tmax; tt += 4) {
        const int s0 = tt * 32;
        const bool lowAct = (tt <= idx);
        const bool mlow = (tt == idx), mhigh = (tt == tmax);
        const int sbeg = lowAct ? 0 : 2;

        bf16x8 ka[2][2];
#pragma unroll
        for (int kst = 0; kst < 2; ++kst)
#pragma unroll
            for (int half = 0; half < 2; ++half)
                ka[kst][half] = *(const bf16x8*)(kb + (size_t)(s0 + kst * 16 + c) * D_
                                                 + half * 32 + quad * 8);
        float4 bx4 = *(const float4*)(biasb + s0 + quad * 4);
        float4 by4 = *(const float4*)(biasb + s0 + 16 + quad * 4);
        const float bx[4] = {bx4.x, bx4.y, bx4.z, bx4.w};
        const float by[4] = {by4.x, by4.y, by4.z, by4.w};

#pragma unroll
        for (int sub = 0; sub < 4; ++sub) {
            if (sub < sbeg) continue;
            f32x4 sx = {0,0,0,0}, sy = {0,0,0,0};
            sx = __builtin_amdgcn_mfma_f32_16x16x32_bf16(ka[0][0], qf[sub][0], sx, 0,0,0);
            sx = __builtin_amdgcn_mfma_f32_16x16x32_bf16(ka[0][1], qf[sub][1], sx, 0,0,0);
            sy = __builtin_amdgcn_mfma_f32_16x16x32_bf16(ka[1][0], qf[sub][0], sy, 0,0,0);
            sy = __builtin_amdgcn_mfma_f32_16x16x32_bf16(ka[1][1], qf[sub][1], sy, 0,0,0);

            float px[4], py[4];
#pragma unroll
            for (int i = 0; i < 4; ++i) {
                px[i] = __builtin_amdgcn_exp2f(fmaf(sx[i], 0.18033688f, bx[i]));
                py[i] = __builtin_amdgcn_exp2f(fmaf(sy[i], 0.18033688f, by[i]));
            }
            const bool msk = (sub < 2) ? mlow : mhigh;
            if (msk) {
                const int qq = (sub & 1) * 16 + c;     // q - s0 within diag tile
#pragma unroll
                for (int i = 0; i < 4; ++i) {
                    if (quad * 4 + i      > qq) px[i] = 0.0f;
                    if (16 + quad * 4 + i > qq) py[i] = 0.0f;
                }
            }
            uint2 wx = {pk2(px[0], px[1]), pk2(px[2], px[3])};
            uint2 wy = {pk2(py[0], py[1]), pk2(py[2], py[3])};
            *(uint2*)(lp + rw[sub] + quad * 8)      = wx;
            *(uint2*)(lp + rw[sub] + 32 + quad * 8) = wy;
        }

        bf16x8 va[4];
#pragma unroll
        for (int dt = 0; dt < 4; ++dt)
            va[dt] = *(const bf16x8*)(vtb + (size_t)(dt * 16 + c) * T_ + s0 + quad * 8);

#pragma unroll
        for (int sub = 0; sub < 4; ++sub) {
            if (sub < sbeg) continue;
            bf16x8 pf = *(const bf16x8*)(lp + rw[sub] + quad * 16);
#pragma unroll
            for (int dt = 0; dt < 4; ++dt)
                o[dt][sub] = __builtin_amdgcn_mfma_f32_16x16x32_bf16(
                    va[dt], pf, o[dt][sub], 0, 0, 0);
            lacc[sub] = __builtin_amdgcn_mfma_f32_16x16x32_bf16(
                onesf, pf, lacc[sub], 0, 0, 0);
        }
    }

    // ---- block merge of 4 partial O^T / l (linear thanks to static max) ----
    // Ob[q_loc][d], pitch 72 floats (18432 B); lb [4 wave][64 q] at +18432.
    float* Ob = (float*)Plds;
    float* lb = (float*)(Plds + 18432);

    __syncthreads();                               // all P reads done
    if (quad == 0) {
#pragma unroll
        for (int sub = 0; sub < 4; ++sub)
            lb[wave * 64 + sub * 16 + c] = lacc[sub][0];
    }
    if (wave == 0) {
#pragma unroll
        for (int sub = 0; sub < 4; ++sub)
#pragma unroll
            for (int dt = 0; dt < 4; ++dt)
                *(f32x4*)&Ob[(sub * 16 + c) * 72 + dt * 16 + quad * 4] = o[dt][sub];
    }
    __syncthreads();
#pragma unroll
    for (int w = 1; w < 4; ++w) {
        if (wave == w) {
#pragma unroll
            for (int sub = 0; sub < 4; ++sub)
#pragma unroll
                for (int dt = 0; dt < 4; ++dt) {
                    float* p = &Ob[(sub * 16 + c) * 72 + dt * 16 + quad * 4];
                    f32x4 t = *(f32x4*)p;
                    t += o[dt][sub];
                    *(f32x4*)p = t;
                }
        }
        __syncthreads();
    }

    // ---- normalize + store: thread -> (q row, 16 consecutive d values) ----
    const int qq = tid >> 2;                       // 0..63
    const int d0 = (tid & 3) * 16;
    const float lsum = lb[qq] + lb[64 + qq] + lb[128 + qq] + lb[192 + qq];
    const float inv = 1.0f / lsum;
    const int tg = (qq < 32) ? (ql0 + qq) : (qh0 + qq - 32);

    bf16x8 r0, r1;
#pragma unroll
    for (int j = 0; j < 8; ++j) {
        r0[j] = f2bf(Ob[qq * 72 + d0 + j] * inv);
        r1[j] = f2bf(Ob[qq * 72 + d0 + 8 + j] * inv);
    }
    short* ab = attn + ((size_t)b * T_ + tg) * E_ + h * D_ + d0;
    *(bf16x8*)ab       = r0;
    *(bf16x8*)(ab + 8) = r1;
}

// ---------------------------------------------------------------------------
extern "C" void kernel_launch(void* const* d_in, const int* in_sizes, int n_in,
                              void* d_out, int out_size, void* d_ws, size_t ws_size,
                              hipStream_t stream) {
    const float* x    = (const float*)d_in[0];
    const float* mask = (const float*)d_in[1];
    const float* Wq   = (const float*)d_in[2];
    const float* Wk   = (const float*)d_in[3];
    const float* Wv   = (const float*)d_in[4];
    const float* Wo   = (const float*)d_in[5];
    const float* bo   = (const float*)d_in[6];
    float* out        = (float*)d_out;

    const size_t S = (size_t)M_ * E_;              // 8.4M elems
    char* ws = (char*)d_ws;
    short* xb   = (short*)ws;                      // bf16 x; reused as attn
    short* qb   = (short*)(ws + S * 2);
    short* kb   = (short*)(ws + S * 4);
    short* vtb  = (short*)(ws + S * 6);            // V stored transposed by MODE0
    short* Wt   = (short*)(ws + S * 8);
    short* Wob  = (short*)(ws + S * 8 + (size_t)3 * 1024 * 1024 * 2);
    float* bias = (float*)(ws + S * 8 + (size_t)4 * 1024 * 1024 * 2);
    short* attnb = xb;

    conv_bf16<<<dim3(M_ * E_ / 1024), 256, 0, stream>>>(x, xb);
    conv_bf16<<<dim3(E_ * E_ / 1024), 256, 0, stream>>>(Wo, Wob);
    wtrans<<<dim3(E_ / 64, H_, 3), 256, 0, stream>>>(Wq, Wk, Wv, Wt);
    bias_prep<<<dim3(B_ * T_ / 256), 256, 0, stream>>>(mask, bias);

    mfma_gemm<0><<<dim3(M_ / 128, 3 * E_ / 128), 256, 0, stream>>>(
        xb, Wt, qb, kb, vtb, nullptr, nullptr);

    flash_attn3<<<dim3(H_, B_, T_ / 64), 256, 0, stream>>>(qb, kb, vtb, bias, attnb);

    mfma_gemm<1><<<dim3(M_ / 128, E_ / 128), 256, 0, stream>>>(
        attnb, Wob, nullptr, nullptr, nullptr, out, bo);
}